// Round 1
// baseline (11724.670 us; speedup 1.0000x reference)
//
#include <hip/hip_runtime.h>

// ChebNet: 3x ChebConv(K=5) + relu, then linear head. N=100000, E=1600000, HID=64.
// fp32 throughout. Props via atomic scatter; dense via register-resident W columns.

#define TB 256

__global__ __launch_bounds__(TB) void k_deg(const int* __restrict__ src,
                                            float* __restrict__ deg, int E) {
    int e = blockIdx.x * TB + threadIdx.x;
    if (e < E) atomicAdd(&deg[src[e]], 1.0f);
}

__global__ __launch_bounds__(TB) void k_dinv(float* __restrict__ deg, int N) {
    int n = blockIdx.x * TB + threadIdx.x;
    if (n < N) {
        float d = deg[n];
        deg[n] = d > 0.f ? rsqrtf(d) : 0.f;
    }
}

__global__ __launch_bounds__(TB) void k_norm(const int* __restrict__ src,
                                             const int* __restrict__ dst,
                                             const float* __restrict__ dinv,
                                             float* __restrict__ norm, int E) {
    int e = blockIdx.x * TB + threadIdx.x;
    if (e < E) norm[e] = -dinv[src[e]] * dinv[dst[e]];
}

// Fin=1 scatter: out[dst] += scale * norm * in[src]
__global__ __launch_bounds__(TB) void k_scatter1(const float* __restrict__ in,
                                                 float* __restrict__ out,
                                                 const int* __restrict__ src,
                                                 const int* __restrict__ dst,
                                                 const float* __restrict__ norm,
                                                 float scale, int E) {
    int e = blockIdx.x * TB + threadIdx.x;
    if (e < E) atomicAdd(&out[dst[e]], scale * norm[e] * in[src[e]]);
}

// out = -in (float4)
__global__ __launch_bounds__(TB) void k_negcopy4(const float4* __restrict__ in,
                                                 float4* __restrict__ out, int n4) {
    int i = blockIdx.x * TB + threadIdx.x;
    if (i < n4) {
        float4 v = in[i];
        out[i] = make_float4(-v.x, -v.y, -v.z, -v.w);
    }
}

// out = relu(in) (float4)
__global__ __launch_bounds__(TB) void k_relu4(const float4* __restrict__ in,
                                              float4* __restrict__ out, int n4) {
    int i = blockIdx.x * TB + threadIdx.x;
    if (i < n4) {
        float4 v = in[i];
        out[i] = make_float4(fmaxf(v.x, 0.f), fmaxf(v.y, 0.f),
                             fmaxf(v.z, 0.f), fmaxf(v.w, 0.f));
    }
}

// Fin=64 scatter: thread = (edge, f-group of 4). Coalesced float4 gather of
// in[src*64 + f4..f4+3], 4 coalesced atomics into out[dst*64 + f4..].
__global__ __launch_bounds__(TB) void k_scatter64(const float* __restrict__ in,
                                                  float* __restrict__ out,
                                                  const int* __restrict__ src,
                                                  const int* __restrict__ dst,
                                                  const float* __restrict__ norm,
                                                  float scale, int E) {
    int tid = blockIdx.x * TB + threadIdx.x;
    if (tid >= E * 16) return;
    int e = tid >> 4;
    int f4 = (tid & 15) * 4;
    int s = src[e], d = dst[e];
    float w = scale * norm[e];
    const float4 v = *(const float4*)(in + (size_t)s * 64 + f4);
    float* o = out + (size_t)d * 64 + f4;
    atomicAdd(o + 0, v.x * w);
    atomicAdd(o + 1, v.y * w);
    atomicAdd(o + 2, v.z * w);
    atomicAdd(o + 3, v.w * w);
}

// acc[n][f] (+)= sum_fin Tx[n][fin] * Wk[fin][f]   (+bias on init)
// Wave-per-node, lane = f. W column (64 floats) lives in registers per lane;
// Tx row read via lane-uniform (broadcast) float4 loads. Grid-stride over nodes.
__global__ __launch_bounds__(TB) void k_matmul(const float* __restrict__ Tx,
                                               const float* __restrict__ Wk,
                                               const float* __restrict__ bias,
                                               float* __restrict__ acc,
                                               int initFlag, int N) {
    int lane = threadIdx.x & 63;
    int wid = blockIdx.x * (TB / 64) + (threadIdx.x >> 6);
    int nw = gridDim.x * (TB / 64);

    float wcol[64];
#pragma unroll
    for (int j = 0; j < 64; ++j) wcol[j] = Wk[j * 64 + lane];
    float bv = bias[lane];

    for (int n = wid; n < N; n += nw) {
        const float4* row = (const float4*)(Tx + (size_t)n * 64);
        float a = initFlag ? bv : acc[(size_t)n * 64 + lane];
#pragma unroll
        for (int j4 = 0; j4 < 16; ++j4) {
            float4 t = row[j4];
            a = fmaf(t.x, wcol[4 * j4 + 0], a);
            a = fmaf(t.y, wcol[4 * j4 + 1], a);
            a = fmaf(t.z, wcol[4 * j4 + 2], a);
            a = fmaf(t.w, wcol[4 * j4 + 3], a);
        }
        acc[(size_t)n * 64 + lane] = a;
    }
}

// Layer 1 combine: h[n][f] = relu(b1[f] + sum_k t_k[n] * W1[k][0][f])
__global__ __launch_bounds__(TB) void k_layer1(const float* __restrict__ x,
                                               const float* __restrict__ t1,
                                               const float* __restrict__ t2,
                                               const float* __restrict__ t3,
                                               const float* __restrict__ t4,
                                               const float* __restrict__ W1,
                                               const float* __restrict__ b1,
                                               float* __restrict__ A, int N) {
    int tid = blockIdx.x * TB + threadIdx.x;
    if (tid >= N * 64) return;
    int n = tid >> 6, f = tid & 63;
    float v = b1[f];
    v = fmaf(x[n],  W1[f],        v);
    v = fmaf(t1[n], W1[64 + f],   v);
    v = fmaf(t2[n], W1[128 + f],  v);
    v = fmaf(t3[n], W1[192 + f],  v);
    v = fmaf(t4[n], W1[256 + f],  v);
    A[tid] = fmaxf(v, 0.f);
}

// Final head: out[n] = bfc + sum_f A[n][f] * Wfc[f]. Wave-per-node reduce.
__global__ __launch_bounds__(TB) void k_final(const float* __restrict__ A,
                                              const float* __restrict__ Wfc,
                                              const float* __restrict__ bfc,
                                              float* __restrict__ out, int N) {
    int lane = threadIdx.x & 63;
    int wid = blockIdx.x * (TB / 64) + (threadIdx.x >> 6);
    if (wid >= N) return;
    float v = A[(size_t)wid * 64 + lane] * Wfc[lane];
#pragma unroll
    for (int o = 32; o > 0; o >>= 1) v += __shfl_down(v, o, 64);
    if (lane == 0) out[wid] = v + bfc[0];
}

extern "C" void kernel_launch(void* const* d_in, const int* in_sizes, int n_in,
                              void* d_out, int out_size, void* d_ws, size_t ws_size,
                              hipStream_t stream) {
    const float* x   = (const float*)d_in[0];
    const int*   ei  = (const int*)d_in[1];
    const float* W1  = (const float*)d_in[2];
    const float* b1  = (const float*)d_in[3];
    const float* W2  = (const float*)d_in[4];
    const float* b2  = (const float*)d_in[5];
    const float* W3  = (const float*)d_in[6];
    const float* b3  = (const float*)d_in[7];
    const float* Wfc = (const float*)d_in[8];
    const float* bfc = (const float*)d_in[9];
    float* out = (float*)d_out;

    const int N = in_sizes[0];
    const int E = in_sizes[1] / 2;
    const int* src = ei;
    const int* dst = ei + E;

    float* ws = (float*)d_ws;
    size_t off = 0;
    float* norm = ws + off; off += (size_t)E;
    float* deg  = ws + off; off += (size_t)N;   // becomes dinv in place
    float* t1   = ws + off; off += (size_t)N;
    float* t2   = ws + off; off += (size_t)N;
    float* t3   = ws + off; off += (size_t)N;
    float* t4   = ws + off; off += (size_t)N;
    float* A    = ws + off; off += (size_t)N * 64;
    float* B    = ws + off; off += (size_t)N * 64;
    float* C    = ws + off; off += (size_t)N * 64;
    float* ACC  = ws + off; off += (size_t)N * 64;

    const int gE   = (E + TB - 1) / TB;
    const int gN   = (N + TB - 1) / TB;
    const int gN4  = (N / 4 + TB - 1) / TB;         // N divisible by 4
    const int gE16 = (int)(((size_t)E * 16 + TB - 1) / TB);
    const int gNF  = (int)(((size_t)N * 64 + TB - 1) / TB);
    const int gNF4 = (int)(((size_t)N * 16 + TB - 1) / TB);
    const int gFin = (N + 3) / 4;                   // 4 waves per block
    const int gMM  = 512;                           // matmul grid-stride blocks

    // --- norm precompute ---
    hipMemsetAsync(deg, 0, (size_t)N * 4, stream);
    k_deg<<<gE, TB, 0, stream>>>(src, deg, E);
    k_dinv<<<gN, TB, 0, stream>>>(deg, N);
    k_norm<<<gE, TB, 0, stream>>>(src, dst, deg, norm, E);

    // --- Layer 1 (Fin=1) ---
    hipMemsetAsync(t1, 0, (size_t)N * 4, stream);
    k_scatter1<<<gE, TB, 0, stream>>>(x, t1, src, dst, norm, 1.f, E);
    k_negcopy4<<<gN4, TB, 0, stream>>>((const float4*)x, (float4*)t2, N / 4);
    k_scatter1<<<gE, TB, 0, stream>>>(t1, t2, src, dst, norm, 2.f, E);
    k_negcopy4<<<gN4, TB, 0, stream>>>((const float4*)t1, (float4*)t3, N / 4);
    k_scatter1<<<gE, TB, 0, stream>>>(t2, t3, src, dst, norm, 2.f, E);
    k_negcopy4<<<gN4, TB, 0, stream>>>((const float4*)t2, (float4*)t4, N / 4);
    k_scatter1<<<gE, TB, 0, stream>>>(t3, t4, src, dst, norm, 2.f, E);
    k_layer1<<<gNF, TB, 0, stream>>>(x, t1, t2, t3, t4, W1, b1, A, N);

    // --- Layers 2 & 3 (Fin=64) ---
    auto layer64 = [&](const float* W, const float* b) {
        // k=0: ACC = b + A @ W0      (A = Tx0)
        k_matmul<<<gMM, TB, 0, stream>>>(A, W + 0 * 4096, b, ACC, 1, N);
        // Tx1 = prop(Tx0) -> B
        hipMemsetAsync(B, 0, (size_t)N * 256, stream);
        k_scatter64<<<gE16, TB, 0, stream>>>(A, B, src, dst, norm, 1.f, E);
        k_matmul<<<gMM, TB, 0, stream>>>(B, W + 1 * 4096, b, ACC, 0, N);
        // Tx2 = 2*prop(Tx1) - Tx0 -> C
        k_negcopy4<<<gNF4, TB, 0, stream>>>((const float4*)A, (float4*)C, N * 16);
        k_scatter64<<<gE16, TB, 0, stream>>>(B, C, src, dst, norm, 2.f, E);
        k_matmul<<<gMM, TB, 0, stream>>>(C, W + 2 * 4096, b, ACC, 0, N);
        // Tx3 = 2*prop(Tx2) - Tx1 -> A (Tx0 dead)
        k_negcopy4<<<gNF4, TB, 0, stream>>>((const float4*)B, (float4*)A, N * 16);
        k_scatter64<<<gE16, TB, 0, stream>>>(C, A, src, dst, norm, 2.f, E);
        k_matmul<<<gMM, TB, 0, stream>>>(A, W + 3 * 4096, b, ACC, 0, N);
        // Tx4 = 2*prop(Tx3) - Tx2 -> B (Tx1 dead)
        k_negcopy4<<<gNF4, TB, 0, stream>>>((const float4*)C, (float4*)B, N * 16);
        k_scatter64<<<gE16, TB, 0, stream>>>(A, B, src, dst, norm, 2.f, E);
        k_matmul<<<gMM, TB, 0, stream>>>(B, W + 4 * 4096, b, ACC, 0, N);
        // h = relu(ACC) -> A (next layer input)
        k_relu4<<<gNF4, TB, 0, stream>>>((const float4*)ACC, (float4*)A, N * 16);
    };
    layer64(W2, b2);
    layer64(W3, b3);

    // --- Final head ---
    k_final<<<gFin, TB, 0, stream>>>(A, Wfc, bfc, out, N);
}

// Round 2
// 2467.421 us; speedup vs baseline: 4.7518x; 4.7518x over previous
//
#include <hip/hip_runtime.h>

// ChebNet: 3x ChebConv(K=5) + relu + linear head. N=100000, E=1600000, HID=64.
// R2: CSR-by-dst gather props (no atomics in the hot path), recurrence folded
// into the gather (scale/scale0), CSR built on-device every call.

#define TB 256

// ---------- norm precompute ----------
__global__ __launch_bounds__(TB) void k_deg(const int* __restrict__ src,
                                            float* __restrict__ deg, int E) {
    int e = blockIdx.x * TB + threadIdx.x;
    if (e < E) atomicAdd(&deg[src[e]], 1.0f);
}

__global__ __launch_bounds__(TB) void k_dinv(float* __restrict__ deg, int N) {
    int n = blockIdx.x * TB + threadIdx.x;
    if (n < N) {
        float d = deg[n];
        deg[n] = d > 0.f ? rsqrtf(d) : 0.f;
    }
}

// ---------- CSR build ----------
__global__ __launch_bounds__(TB) void k_hist(const int* __restrict__ dst,
                                             int* __restrict__ cnt, int E) {
    int e = blockIdx.x * TB + threadIdx.x;
    if (e < E) atomicAdd(&cnt[dst[e]], 1);
}

// per-block exclusive scan; block totals to bsum
__global__ __launch_bounds__(TB) void k_scan_a(const int* __restrict__ cnt,
                                               int* __restrict__ excl,
                                               int* __restrict__ bsum, int N) {
    __shared__ int s[TB];
    int t = threadIdx.x;
    int i = blockIdx.x * TB + t;
    int v = (i < N) ? cnt[i] : 0;
    s[t] = v;
    __syncthreads();
    for (int o = 1; o < TB; o <<= 1) {
        int add = (t >= o) ? s[t - o] : 0;
        __syncthreads();
        s[t] += add;
        __syncthreads();
    }
    if (i < N) excl[i] = s[t] - v;
    if (t == TB - 1) bsum[blockIdx.x] = s[t];
}

// single-block exclusive scan of block sums (nb <= 1024)
__global__ __launch_bounds__(1024) void k_scan_b(int* __restrict__ bsum, int nb) {
    __shared__ int s[1024];
    int t = threadIdx.x;
    int v = (t < nb) ? bsum[t] : 0;
    s[t] = v;
    __syncthreads();
    for (int o = 1; o < 1024; o <<= 1) {
        int add = (t >= o) ? s[t - o] : 0;
        __syncthreads();
        s[t] += add;
        __syncthreads();
    }
    if (t < nb) bsum[t] = s[t] - v;
}

// add block offsets; write rowptr + cursor copy; rowptr[N] = E
__global__ __launch_bounds__(TB) void k_scan_c(int* __restrict__ rowptr,
                                               int* __restrict__ wr,
                                               const int* __restrict__ bsum,
                                               int N, int E) {
    int i = blockIdx.x * TB + threadIdx.x;
    if (i < N) {
        int r = rowptr[i] + bsum[blockIdx.x];
        rowptr[i] = r;
        wr[i] = r;
    }
    if (i == 0) rowptr[N] = E;
}

// fill CSR: packed (src, norm) per edge, bucketed by dst
__global__ __launch_bounds__(TB) void k_fill(const int* __restrict__ src,
                                             const int* __restrict__ dst,
                                             const float* __restrict__ dinv,
                                             int* __restrict__ wr,
                                             int2* __restrict__ csr, int E) {
    int e = blockIdx.x * TB + threadIdx.x;
    if (e < E) {
        int s = src[e], d = dst[e];
        float w = -dinv[s] * dinv[d];
        int pos = atomicAdd(&wr[d], 1);
        csr[pos] = make_int2(s, __float_as_int(w));
    }
}

// ---------- props (gather) ----------
// out[n] = scale * sum_{e in row n} w_e * in[src_e]  +  scale0 * prev[n]
__global__ __launch_bounds__(TB) void k_gather1(const float* __restrict__ in,
                                                const float* __restrict__ prev,
                                                float* __restrict__ out,
                                                const int* __restrict__ rowptr,
                                                const int2* __restrict__ csr,
                                                float scale, float scale0, int N) {
    int n = blockIdx.x * TB + threadIdx.x;
    if (n >= N) return;
    int beg = rowptr[n], end = rowptr[n + 1];
    float s = 0.f;
    for (int i = beg; i < end; ++i) {
        int2 e = csr[i];
        s = fmaf(__int_as_float(e.y), in[e.x], s);
    }
    out[n] = fmaf(scale, s, scale0 * prev[n]);
}

// wave-per-node, lane = feature. out[n][f] = scale*sum w*in[src][f] + scale0*prev[n][f]
__global__ __launch_bounds__(TB) void k_gather64(const float* __restrict__ in,
                                                 const float* __restrict__ prev,
                                                 float* __restrict__ out,
                                                 const int* __restrict__ rowptr,
                                                 const int2* __restrict__ csr,
                                                 float scale, float scale0, int N) {
    int lane = threadIdx.x & 63;
    int n = blockIdx.x * (TB / 64) + (threadIdx.x >> 6);
    if (n >= N) return;
    int beg = rowptr[n], end = rowptr[n + 1];
    float s = 0.f;
    for (int i = beg; i < end; ++i) {
        int2 e = csr[i];
        s = fmaf(__int_as_float(e.y), in[(size_t)e.x * 64 + lane], s);
    }
    out[(size_t)n * 64 + lane] = fmaf(scale, s, scale0 * prev[(size_t)n * 64 + lane]);
}

// ---------- dense ----------
// acc[n][f] (+)= sum_fin Tx[n][fin] * Wk[fin][f]  (+bias on init)
__global__ __launch_bounds__(TB) void k_matmul(const float* __restrict__ Tx,
                                               const float* __restrict__ Wk,
                                               const float* __restrict__ bias,
                                               float* __restrict__ acc,
                                               int initFlag, int N) {
    int lane = threadIdx.x & 63;
    int wid = blockIdx.x * (TB / 64) + (threadIdx.x >> 6);
    int nw = gridDim.x * (TB / 64);

    float wcol[64];
#pragma unroll
    for (int j = 0; j < 64; ++j) wcol[j] = Wk[j * 64 + lane];
    float bv = bias[lane];

    for (int n = wid; n < N; n += nw) {
        const float4* row = (const float4*)(Tx + (size_t)n * 64);
        float a = initFlag ? bv : acc[(size_t)n * 64 + lane];
#pragma unroll
        for (int j4 = 0; j4 < 16; ++j4) {
            float4 t = row[j4];
            a = fmaf(t.x, wcol[4 * j4 + 0], a);
            a = fmaf(t.y, wcol[4 * j4 + 1], a);
            a = fmaf(t.z, wcol[4 * j4 + 2], a);
            a = fmaf(t.w, wcol[4 * j4 + 3], a);
        }
        acc[(size_t)n * 64 + lane] = a;
    }
}

// Layer 1 combine: h[n][f] = relu(b1[f] + sum_k t_k[n] * W1[k][0][f])
__global__ __launch_bounds__(TB) void k_layer1(const float* __restrict__ x,
                                               const float* __restrict__ t1,
                                               const float* __restrict__ t2,
                                               const float* __restrict__ t3,
                                               const float* __restrict__ t4,
                                               const float* __restrict__ W1,
                                               const float* __restrict__ b1,
                                               float* __restrict__ A, int N) {
    int tid = blockIdx.x * TB + threadIdx.x;
    if (tid >= N * 64) return;
    int n = tid >> 6, f = tid & 63;
    float v = b1[f];
    v = fmaf(x[n],  W1[f],       v);
    v = fmaf(t1[n], W1[64 + f],  v);
    v = fmaf(t2[n], W1[128 + f], v);
    v = fmaf(t3[n], W1[192 + f], v);
    v = fmaf(t4[n], W1[256 + f], v);
    A[tid] = fmaxf(v, 0.f);
}

__global__ __launch_bounds__(TB) void k_relu4(const float4* __restrict__ in,
                                              float4* __restrict__ out, int n4) {
    int i = blockIdx.x * TB + threadIdx.x;
    if (i < n4) {
        float4 v = in[i];
        out[i] = make_float4(fmaxf(v.x, 0.f), fmaxf(v.y, 0.f),
                             fmaxf(v.z, 0.f), fmaxf(v.w, 0.f));
    }
}

__global__ __launch_bounds__(TB) void k_final(const float* __restrict__ A,
                                              const float* __restrict__ Wfc,
                                              const float* __restrict__ bfc,
                                              float* __restrict__ out, int N) {
    int lane = threadIdx.x & 63;
    int wid = blockIdx.x * (TB / 64) + (threadIdx.x >> 6);
    if (wid >= N) return;
    float v = A[(size_t)wid * 64 + lane] * Wfc[lane];
#pragma unroll
    for (int o = 32; o > 0; o >>= 1) v += __shfl_down(v, o, 64);
    if (lane == 0) out[wid] = v + bfc[0];
}

extern "C" void kernel_launch(void* const* d_in, const int* in_sizes, int n_in,
                              void* d_out, int out_size, void* d_ws, size_t ws_size,
                              hipStream_t stream) {
    const float* x   = (const float*)d_in[0];
    const int*   ei  = (const int*)d_in[1];
    const float* W1  = (const float*)d_in[2];
    const float* b1  = (const float*)d_in[3];
    const float* W2  = (const float*)d_in[4];
    const float* b2  = (const float*)d_in[5];
    const float* W3  = (const float*)d_in[6];
    const float* b3  = (const float*)d_in[7];
    const float* Wfc = (const float*)d_in[8];
    const float* bfc = (const float*)d_in[9];
    float* out = (float*)d_out;

    const int N = in_sizes[0];
    const int E = in_sizes[1] / 2;
    const int* src = ei;
    const int* dst = ei + E;

    // workspace layout
    float* ws = (float*)d_ws;
    float* A    = ws;
    float* B    = A   + (size_t)N * 64;
    float* C    = B   + (size_t)N * 64;
    float* ACC  = C   + (size_t)N * 64;
    float* t1   = ACC + (size_t)N * 64;
    float* t2   = t1 + N;
    float* t3   = t2 + N;
    float* t4   = t3 + N;
    float* deg  = t4 + N;                 // becomes dinv in place
    int2*  csr  = (int2*)(deg + N);       // E entries (byte offset is 8-aligned)
    int* rowptr = (int*)(csr + E);        // N+1
    int* wr     = rowptr + N + 1;         // N
    int* cnt    = wr + N;                 // N
    int* bsum   = cnt + N;                // <=1024

    const int gE   = (E + TB - 1) / TB;
    const int gN   = (N + TB - 1) / TB;   // also #scan blocks (<=1024 assumed)
    const int gNW  = (N + 3) / 4;         // wave-per-node blocks (4 waves/block)
    const int gNF  = (int)(((size_t)N * 64 + TB - 1) / TB);
    const int gNF4 = (int)(((size_t)N * 16 + TB - 1) / TB);
    const int gMM  = 512;

    // norm + CSR build
    hipMemsetAsync(deg, 0, (size_t)N * 4, stream);
    hipMemsetAsync(cnt, 0, (size_t)N * 4, stream);
    k_deg<<<gE, TB, 0, stream>>>(src, deg, E);
    k_dinv<<<gN, TB, 0, stream>>>(deg, N);
    k_hist<<<gE, TB, 0, stream>>>(dst, cnt, E);
    k_scan_a<<<gN, TB, 0, stream>>>(cnt, rowptr, bsum, N);
    k_scan_b<<<1, 1024, 0, stream>>>(bsum, gN);
    k_scan_c<<<gN, TB, 0, stream>>>(rowptr, wr, bsum, N, E);
    k_fill<<<gE, TB, 0, stream>>>(src, dst, deg, wr, csr, E);

    // --- Layer 1 (Fin=1) ---
    k_gather1<<<gN, TB, 0, stream>>>(x,  x,  t1, rowptr, csr, 1.f,  0.f, N);
    k_gather1<<<gN, TB, 0, stream>>>(t1, x,  t2, rowptr, csr, 2.f, -1.f, N);
    k_gather1<<<gN, TB, 0, stream>>>(t2, t1, t3, rowptr, csr, 2.f, -1.f, N);
    k_gather1<<<gN, TB, 0, stream>>>(t3, t2, t4, rowptr, csr, 2.f, -1.f, N);
    k_layer1<<<gNF, TB, 0, stream>>>(x, t1, t2, t3, t4, W1, b1, A, N);

    // --- Layers 2 & 3 (Fin=64) ---
    auto layer64 = [&](const float* W, const float* b) {
        k_matmul<<<gMM, TB, 0, stream>>>(A, W + 0 * 4096, b, ACC, 1, N);
        k_gather64<<<gNW, TB, 0, stream>>>(A, A, B, rowptr, csr, 1.f,  0.f, N); // Tx1
        k_matmul<<<gMM, TB, 0, stream>>>(B, W + 1 * 4096, b, ACC, 0, N);
        k_gather64<<<gNW, TB, 0, stream>>>(B, A, C, rowptr, csr, 2.f, -1.f, N); // Tx2
        k_matmul<<<gMM, TB, 0, stream>>>(C, W + 2 * 4096, b, ACC, 0, N);
        k_gather64<<<gNW, TB, 0, stream>>>(C, B, A, rowptr, csr, 2.f, -1.f, N); // Tx3
        k_matmul<<<gMM, TB, 0, stream>>>(A, W + 3 * 4096, b, ACC, 0, N);
        k_gather64<<<gNW, TB, 0, stream>>>(A, C, B, rowptr, csr, 2.f, -1.f, N); // Tx4
        k_matmul<<<gMM, TB, 0, stream>>>(B, W + 4 * 4096, b, ACC, 0, N);
        k_relu4<<<gNF4, TB, 0, stream>>>((const float4*)ACC, (float4*)A, N * 16);
    };
    layer64(W2, b2);
    layer64(W3, b3);

    // --- Final head ---
    k_final<<<gNW, TB, 0, stream>>>(A, Wfc, bfc, out, N);
}